// Round 17
// baseline (8681.061 us; speedup 1.0000x reference)
//
#include <hip/hip_runtime.h>
#include <math.h>

// DummyRNN: h = tanh(x_t*w_ih + b_ih + W_hh@h + b_hh); y_t = W_out@h + b_out
//
// R17 = R16 compute body (16 XCD-co-located chains, W_hh bf16 in LDS, tree
// transpose-reduce, y parked in LDS, roster + per-chain static fast/slow)
// + R11's FUSED LL protocol: {f32 h, u32 tag} pairs, publish fire-and-forget
// (no vmcnt, no flags), the sweep that detects tag==t already carries the
// data -> ONE dependent L2 crossing per step instead of flag-split's three.
// Fused was only ever measured WITH the W-rereads-from-L2 confound (R9/R11);
// R12 proved W traffic was the saturator. This is the untested cell:
// fused + LDS-W. Demote/abort machinery copied from R11 (passed).

#define H      1024
#define TSTEPS 20480
#define BLOCK  256
#define RPW    16
#define WARM   64
#define WGSPC  16
#define NCHC   16
#define NCHF   4

typedef unsigned int uint;
typedef unsigned long long u64;
typedef unsigned int u32x4 __attribute__((ext_vector_type(4)));

#define PAIRS_BYTES ((size_t)NCHC * 2 * H * sizeof(u64))   // 256 KB

__device__ __forceinline__ uint f2bf(float f) {            // fp32 -> bf16 RNE
    uint u = __float_as_uint(f);
    return (u + 0x7fffu + ((u >> 16) & 1u)) >> 16;
}

__device__ __forceinline__ void sweep8(bool fast, const char* a0, const char* a1,
    u32x4& L0, u32x4& L1, u32x4& L2, u32x4& L3,
    u32x4& L4, u32x4& L5, u32x4& L6, u32x4& L7)
{
    if (fast) {
        asm volatile(
            "global_load_dwordx4 %0, %8, off sc0\n\t"
            "global_load_dwordx4 %1, %8, off offset:1024 sc0\n\t"
            "global_load_dwordx4 %2, %8, off offset:2048 sc0\n\t"
            "global_load_dwordx4 %3, %8, off offset:3072 sc0\n\t"
            "global_load_dwordx4 %4, %9, off sc0\n\t"
            "global_load_dwordx4 %5, %9, off offset:1024 sc0\n\t"
            "global_load_dwordx4 %6, %9, off offset:2048 sc0\n\t"
            "global_load_dwordx4 %7, %9, off offset:3072 sc0\n\t"
            "s_waitcnt vmcnt(0)"
            : "=&v"(L0), "=&v"(L1), "=&v"(L2), "=&v"(L3),
              "=&v"(L4), "=&v"(L5), "=&v"(L6), "=&v"(L7)
            : "v"(a0), "v"(a1) : "memory");
    } else {
        asm volatile(
            "global_load_dwordx4 %0, %8, off sc0 sc1\n\t"
            "global_load_dwordx4 %1, %8, off offset:1024 sc0 sc1\n\t"
            "global_load_dwordx4 %2, %8, off offset:2048 sc0 sc1\n\t"
            "global_load_dwordx4 %3, %8, off offset:3072 sc0 sc1\n\t"
            "global_load_dwordx4 %4, %9, off sc0 sc1\n\t"
            "global_load_dwordx4 %5, %9, off offset:1024 sc0 sc1\n\t"
            "global_load_dwordx4 %6, %9, off offset:2048 sc0 sc1\n\t"
            "global_load_dwordx4 %7, %9, off offset:3072 sc0 sc1\n\t"
            "s_waitcnt vmcnt(0)"
            : "=&v"(L0), "=&v"(L1), "=&v"(L2), "=&v"(L3),
              "=&v"(L4), "=&v"(L5), "=&v"(L6), "=&v"(L7)
            : "v"(a0), "v"(a1) : "memory");
    }
}

__global__ __launch_bounds__(BLOCK, 1)
void rnn_r17(const float* __restrict__ xs, const float* __restrict__ W_ih,
             const float* __restrict__ b_ih, const float* __restrict__ W_hh,
             const float* __restrict__ b_hh, const float* __restrict__ W_out,
             const float* __restrict__ b_out, float* __restrict__ y,
             u64* __restrict__ pairs, uint* __restrict__ ctrl,
             int coop, int chunk)
{
    const int tid  = threadIdx.x;
    const int bid  = blockIdx.x;
    const int wave = tid >> 6;
    const int lane = tid & 63;

    __shared__ uint  sW[64][512];    // 128 KB: 64 rows of W_hh as bf16 pairs
    __shared__ uint  sR[256];
    __shared__ int   sA[3];
    __shared__ float sY[4][84];      // parked y values

    uint* rcount = ctrl;             // [0]
    uint* abortf = ctrl + 16;        // [16..31] per-chain abort flags
    uint* roster = ctrl + 64;        // [64..319]

    int chain, slot; bool fastm;
    if (coop) {
        uint xcc = __builtin_amdgcn_s_getreg(20 | (31 << 11)) & 7u; // HW_REG_XCC_ID
        if (tid == 0) {
            __hip_atomic_store(&roster[bid], xcc, __ATOMIC_RELAXED, __HIP_MEMORY_SCOPE_AGENT);
            asm volatile("s_waitcnt vmcnt(0)" ::: "memory");
            atomicAdd(rcount, 1u);
            while (__hip_atomic_load(rcount, __ATOMIC_RELAXED, __HIP_MEMORY_SCOPE_AGENT) < 256u)
                __builtin_amdgcn_s_sleep(2);
        }
        __syncthreads();
        sR[tid] = __hip_atomic_load(&roster[tid], __ATOMIC_RELAXED, __HIP_MEMORY_SCOPE_AGENT);
        __syncthreads();
        if (tid == 0) {
            // order blocks by (xcd, index rank); chain = 16 consecutive
            // blocks; FAST iff the chain lies within one XCD's segment.
            int cnt[8] = {0,0,0,0,0,0,0,0};
            int myrank = 0, myx = 0;
            for (int b = 0; b < 256; ++b) {
                int x = (int)(sR[b] & 7u);
                int r = cnt[x]++;
                if (b == bid) { myrank = r; myx = x; }
            }
            int pre[9]; pre[0] = 0;
            for (int x = 0; x < 8; ++x) pre[x + 1] = pre[x] + cnt[x];
            int gidx = pre[myx] + myrank;
            int ch = gidx >> 4, sl = gidx & 15;
            int lo = ch << 4, hi = lo + 16, fok = 0;
            for (int x = 0; x < 8; ++x)
                if (pre[x] <= lo && hi <= pre[x + 1]) fok = 1;
            sA[0] = ch; sA[1] = sl; sA[2] = fok;
        }
        __syncthreads();
        chain = sA[0]; slot = sA[1]; fastm = (sA[2] != 0);
    } else {
        chain = bid / WGSPC; slot = bid % WGSPC; fastm = false;
    }

    u64*  pb     = pairs + (size_t)chain * 2 * H;
    uint* abortp = abortf + chain;
    const int wic     = slot * 4 + wave;       // wave-in-chain 0..63
    const int rowbase = slot * 64 + wave * 16; // this wave's 16 rows
    const int rowwg   = slot * 64;

    // ---- one-time: stage the WG's 64 W_hh rows into LDS as bf16 pairs ----
    for (int idx = tid; idx < 64 * 512; idx += BLOCK) {
        const int r = idx >> 9, p = idx & 511;
        const float2 w = *(const float2*)&W_hh[(size_t)(rowwg + r) * H + 2 * p];
        sW[r][p] = f2bf(w.x) | (f2bf(w.y) << 16);
    }
    __syncthreads();

    const int t0    = chain * chunk - (chain ? WARM : 0);
    const int nstep = chunk + (chain ? WARM : 0);

    const int myrow = rowbase + (lane & 15);
    const float wih_s = W_ih[myrow];
    const float cb_s  = b_ih[myrow] + b_hh[myrow];

    // y weights for this lane's h columns (2l+128j, 2l+1+128j)
    float2 wo2[8];
    #pragma unroll
    for (int j = 0; j < 8; ++j)
        wo2[j] = *(const float2*)&W_out[128 * j + 2 * lane];
    const float bo = b_out[0];

    float hr[16];                    // hr[2j+i] = h[2l + i + 128j]
    u64 lp0 = 0, lp1 = 0;            // last pair published per parity

    // demote to LLC protocol: republish owned pairs sc1 (R11-proven)
    auto demote = [&]() {
        if (lane < 16) {
            u64* q0 = pb + rowbase + (lane & 15);
            u64* q1 = q0 + H;
            asm volatile("global_store_dwordx2 %0, %1, off sc0 sc1"
                         :: "v"(q0), "v"(lp0) : "memory");
            asm volatile("global_store_dwordx2 %0, %1, off sc0 sc1"
                         :: "v"(q1), "v"(lp1) : "memory");
        }
        asm volatile("s_waitcnt vmcnt(0)" ::: "memory");
        if (lane == 0)
            asm volatile("global_store_dword %0, %1, off sc0 sc1"
                         :: "v"(abortp), "v"(1u) : "memory");
        asm volatile("s_waitcnt vmcnt(0)" ::: "memory");
        fastm = false;
    };

    auto abort_set = [&]() -> bool {
        uint ab;
        asm volatile("global_load_dword %0, %1, off sc0 sc1\n\ts_waitcnt vmcnt(0)"
                     : "=v"(ab) : "v"(abortp) : "memory");
        return __any(ab != 0u);
    };

    // fused poll: sweep this lane's 16 pairs until every tag == lt
    auto poll_load = [&](int lt) {
        const u64* sin = pb + (size_t)(lt & 1) * H;
        const char* a0 = (const char*)(sin + 2 * lane);  // pairs 2l,2l+1 (+128j)
        const char* a1 = a0 + 4096;                      // j = 4..7
        const uint tt = (uint)lt;
        u32x4 L0, L1, L2, L3, L4, L5, L6, L7;
        uint fails = 0;
        for (;;) {
            sweep8(fastm, a0, a1, L0, L1, L2, L3, L4, L5, L6, L7);
            bool ok = (L0[1] == tt) & (L0[3] == tt) & (L1[1] == tt) & (L1[3] == tt)
                    & (L2[1] == tt) & (L2[3] == tt) & (L3[1] == tt) & (L3[3] == tt)
                    & (L4[1] == tt) & (L4[3] == tt) & (L5[1] == tt) & (L5[3] == tt)
                    & (L6[1] == tt) & (L6[3] == tt) & (L7[1] == tt) & (L7[3] == tt);
            if (__all(ok)) break;
            ++fails;
            if (fastm) {
                if ((fails & 63u) == 0u) {
                    if (abort_set() || fails > 8192u) demote();
                }
                __builtin_amdgcn_s_sleep(4);   // keep sweep rate under L2 svc
            } else {
                __builtin_amdgcn_s_sleep(8);
            }
        }
        hr[ 0] = __uint_as_float(L0[0]); hr[ 1] = __uint_as_float(L0[2]);
        hr[ 2] = __uint_as_float(L1[0]); hr[ 3] = __uint_as_float(L1[2]);
        hr[ 4] = __uint_as_float(L2[0]); hr[ 5] = __uint_as_float(L2[2]);
        hr[ 6] = __uint_as_float(L3[0]); hr[ 7] = __uint_as_float(L3[2]);
        hr[ 8] = __uint_as_float(L4[0]); hr[ 9] = __uint_as_float(L4[2]);
        hr[10] = __uint_as_float(L5[0]); hr[11] = __uint_as_float(L5[2]);
        hr[12] = __uint_as_float(L6[0]); hr[13] = __uint_as_float(L6[2]);
        hr[14] = __uint_as_float(L7[0]); hr[15] = __uint_as_float(L7[2]);
    };

    const int ymin = (chain ? WARM : 0) + 1;
    float* yc = y + t0;
    float xcur = xs[t0];

    #pragma unroll 1
    for (int lt = 0; lt < nstep; ++lt) {
        if (fastm && (lt & 31) == 1) {          // producer-side liveness
            if (abort_set()) demote();
        }

        poll_load(lt);                          // hr = h_lt (data rode along)

        // 16 row-dots from LDS: pair p = lane + 64j holds cols (2l,2l+1)+128j
        float z[RPW];
        #pragma unroll
        for (int r = 0; r < RPW; ++r) {
            const uint* wrow = &sW[wave * RPW + r][lane];
            float acc = 0.0f;
            #pragma unroll
            for (int j = 0; j < 8; ++j) {
                const uint u = wrow[64 * j];
                acc = fmaf(__uint_as_float(u << 16),         hr[2 * j + 0], acc);
                acc = fmaf(__uint_as_float(u & 0xffff0000u), hr[2 * j + 1], acc);
            }
            z[r] = acc;
        }

        // tree transpose-reduce: lane l ends with full z of row rowbase+(l&15)
        float s0,s1,s2,s3,s4,s5,s6,s7;
        {
            const bool b = (lane & 1) != 0;
            s0 = (b ? z[ 1] : z[ 0]) + __shfl_xor(b ? z[ 0] : z[ 1], 1);
            s1 = (b ? z[ 3] : z[ 2]) + __shfl_xor(b ? z[ 2] : z[ 3], 1);
            s2 = (b ? z[ 5] : z[ 4]) + __shfl_xor(b ? z[ 4] : z[ 5], 1);
            s3 = (b ? z[ 7] : z[ 6]) + __shfl_xor(b ? z[ 6] : z[ 7], 1);
            s4 = (b ? z[ 9] : z[ 8]) + __shfl_xor(b ? z[ 8] : z[ 9], 1);
            s5 = (b ? z[11] : z[10]) + __shfl_xor(b ? z[10] : z[11], 1);
            s6 = (b ? z[13] : z[12]) + __shfl_xor(b ? z[12] : z[13], 1);
            s7 = (b ? z[15] : z[14]) + __shfl_xor(b ? z[14] : z[15], 1);
        }
        float t0_,t1_,t2_,t3_;
        {
            const bool b = (lane & 2) != 0;
            t0_ = (b ? s1 : s0) + __shfl_xor(b ? s0 : s1, 2);
            t1_ = (b ? s3 : s2) + __shfl_xor(b ? s2 : s3, 2);
            t2_ = (b ? s5 : s4) + __shfl_xor(b ? s4 : s5, 2);
            t3_ = (b ? s7 : s6) + __shfl_xor(b ? s6 : s7, 2);
        }
        float u0_,u1_;
        {
            const bool b = (lane & 4) != 0;
            u0_ = (b ? t1_ : t0_) + __shfl_xor(b ? t0_ : t1_, 4);
            u1_ = (b ? t3_ : t2_) + __shfl_xor(b ? t2_ : t3_, 4);
        }
        float zr;
        {
            const bool b = (lane & 8) != 0;
            zr = (b ? u1_ : u0_) + __shfl_xor(b ? u0_ : u1_, 8);
        }
        zr += __shfl_xor(zr, 16);
        zr += __shfl_xor(zr, 32);

        const float hv = tanhf(fmaf(xcur, wih_s, cb_s + zr));

        // publish h_{lt+1}: fused {h,tag} pairs, FIRE-AND-FORGET (no vmcnt)
        {
            u64* sout = pb + (size_t)((lt + 1) & 1) * H;
            const u64 v = ((u64)(uint)(lt + 1) << 32) | (u64)__float_as_uint(hv);
            u64* addr = sout + rowbase + lane;
            if (lane < 16) {
                if (fastm)
                    asm volatile("global_store_dwordx2 %0, %1, off"
                                 :: "v"(addr), "v"(v) : "memory");
                else
                    asm volatile("global_store_dwordx2 %0, %1, off sc0 sc1"
                                 :: "v"(addr), "v"(v) : "memory");
            }
            if (((lt + 1) & 1) == 0) lp0 = v; else lp1 = v;
        }

        // y[t0+lt-1]: duty wave (lt mod 64) -> park in LDS
        if (wic == (lt & 63) && lt >= ymin) {
            float acc = 0.0f;
            #pragma unroll
            for (int j = 0; j < 8; ++j) {
                acc = fmaf(wo2[j].x, hr[2 * j + 0], acc);
                acc = fmaf(wo2[j].y, hr[2 * j + 1], acc);
            }
            #pragma unroll
            for (int off = 32; off > 0; off >>= 1)
                acc += __shfl_xor(acc, off);
            if (lane == 0) sY[wave][lt >> 6] = acc + bo;
        }

        if (lt + 1 < nstep) xcur = xs[t0 + lt + 1];   // prefetch next x
    }

    // ---- flush parked y values: lt = 64*k + wic -> y[t0+lt-1] ----
    #pragma unroll 1
    for (int k = lane; k < 84; k += 64) {
        const int lt = (k << 6) + wic;
        if (lt >= ymin && lt < nstep)
            yc[lt - 1] = sY[wave][k];
    }

    // tail: y[t0+nstep-1] from h_nstep
    if (slot == 0 && wave == 0) {
        poll_load(nstep);
        float acc = 0.0f;
        #pragma unroll
        for (int j = 0; j < 8; ++j) {
            acc = fmaf(wo2[j].x, hr[2 * j + 0], acc);
            acc = fmaf(wo2[j].y, hr[2 * j + 1], acc);
        }
        #pragma unroll
        for (int off = 32; off > 0; off >>= 1)
            acc += __shfl_xor(acc, off);
        if (lane == 0) yc[nstep - 1] = acc + bo;
    }
}

extern "C" void kernel_launch(void* const* d_in, const int* in_sizes, int n_in,
                              void* d_out, int out_size, void* d_ws, size_t ws_size,
                              hipStream_t stream) {
    const float* xs    = (const float*)d_in[0];
    const float* W_ih  = (const float*)d_in[1];
    const float* b_ih  = (const float*)d_in[2];
    const float* W_hh  = (const float*)d_in[3];
    const float* b_hh  = (const float*)d_in[4];
    const float* W_out = (const float*)d_in[5];
    const float* b_out = (const float*)d_in[6];
    float* y    = (float*)d_out;
    u64*  pairs = (u64*)d_ws;
    uint* ctrl  = (uint*)((char*)d_ws + PAIRS_BYTES);

    const size_t need = PAIRS_BYTES + 4096;
    int use_coop = (ws_size >= need) ? 1 : 0;

    (void)hipMemsetAsync(d_ws, 0,
                         use_coop ? need : (size_t)NCHF * 2 * H * sizeof(u64),
                         stream);

    if (use_coop) {
        int coop = 1, chunk = TSTEPS / NCHC;
        void* args[] = { (void*)&xs, (void*)&W_ih, (void*)&b_ih, (void*)&W_hh,
                         (void*)&b_hh, (void*)&W_out, (void*)&b_out, (void*)&y,
                         (void*)&pairs, (void*)&ctrl, (void*)&coop, (void*)&chunk };
        hipError_t e = hipLaunchCooperativeKernel((const void*)rnn_r17,
                                                  dim3(256), dim3(BLOCK),
                                                  args, 0, stream);
        if (e != hipSuccess) use_coop = 0;
    }
    if (!use_coop) {
        rnn_r17<<<NCHF * WGSPC, BLOCK, 0, stream>>>(
            xs, W_ih, b_ih, W_hh, b_hh, W_out, b_out, y,
            pairs, ctrl, 0, TSTEPS / NCHF);
    }
}

// Round 18
// 5708.193 us; speedup vs baseline: 1.5208x; 1.5208x over previous
//
#include <hip/hip_runtime.h>
#include <math.h>

// DummyRNN: h = tanh(x_t*w_ih + b_ih + W_hh@h + b_hh); y_t = W_out@h + b_out
//
// R18: 4-way CHAIN INTERLEAVE. All chains share the same W row-partition, so
// each WG (64 W_hh rows in LDS, staged once) serves 4 chains round-robin:
// poll k -> compute k -> publish k -> next. All WGs rotate in the same order,
// so the 4 chains pipeline: chain k's barrier latency hides under chains
// k+1..k+3's compute. 64 chains x 320 steps (+64 warm) = 384 rotations.
// Protocol per chain = R16's proven flag-split through XCD L2 (per-wave
// flags, data->vmcnt->flag, static per-group fast/slow from XCC roster,
// group demote escape hatch). Fallback: 4 chains, 64 WGs, all-slow, ilv=1.

#define H      1024
#define TSTEPS 20480
#define BLOCK  256
#define RPW    16
#define WARM   64
#define WGSPC  16

typedef unsigned int uint;
typedef float f32x4 __attribute__((ext_vector_type(4)));

#define HDATA_BYTES ((size_t)64 * 2 * H * sizeof(float))   // 512 KB (coop)

__device__ __forceinline__ uint f2bf(float f) {            // fp32 -> bf16 RNE
    uint u = __float_as_uint(f);
    return (u + 0x7fffu + ((u >> 16) & 1u)) >> 16;
}

__global__ __launch_bounds__(BLOCK, 1)
void rnn_r18(const float* __restrict__ xs, const float* __restrict__ W_ih,
             const float* __restrict__ b_ih, const float* __restrict__ W_hh,
             const float* __restrict__ b_hh, const float* __restrict__ W_out,
             const float* __restrict__ b_out, float* __restrict__ y,
             float* __restrict__ hdata, uint* __restrict__ ctrl,
             int coop, int ilv, int chunk)
{
    const int tid  = threadIdx.x;
    const int bid  = blockIdx.x;
    const int wave = tid >> 6;
    const int lane = tid & 63;

    __shared__ uint  sW[64][512];    // 128 KB: 64 rows of W_hh as bf16 pairs
    __shared__ uint  sR[256];
    __shared__ int   sA[3];
    __shared__ float sY[4][4][8];    // [wave][k][rotation>>6] parked y (coop)

    uint* rcount = ctrl;             // [0]
    uint* abortf = ctrl + 16;        // [16..31] per-GROUP abort flags
    uint* roster = ctrl + 64;        // [64..319]
    uint* flbase = ctrl + 1024;      // 64 chains x 64 per-wave flags

    int group, slot; bool fastm;
    if (coop) {
        uint xcc = __builtin_amdgcn_s_getreg(20 | (31 << 11)) & 7u; // HW_REG_XCC_ID
        if (tid == 0) {
            __hip_atomic_store(&roster[bid], xcc, __ATOMIC_RELAXED, __HIP_MEMORY_SCOPE_AGENT);
            asm volatile("s_waitcnt vmcnt(0)" ::: "memory");
            atomicAdd(rcount, 1u);
            while (__hip_atomic_load(rcount, __ATOMIC_RELAXED, __HIP_MEMORY_SCOPE_AGENT) < 256u)
                __builtin_amdgcn_s_sleep(2);
        }
        __syncthreads();
        sR[tid] = __hip_atomic_load(&roster[tid], __ATOMIC_RELAXED, __HIP_MEMORY_SCOPE_AGENT);
        __syncthreads();
        if (tid == 0) {
            int cnt[8] = {0,0,0,0,0,0,0,0};
            int myrank = 0, myx = 0;
            for (int b = 0; b < 256; ++b) {
                int x = (int)(sR[b] & 7u);
                int r = cnt[x]++;
                if (b == bid) { myrank = r; myx = x; }
            }
            int pre[9]; pre[0] = 0;
            for (int x = 0; x < 8; ++x) pre[x + 1] = pre[x] + cnt[x];
            int gidx = pre[myx] + myrank;
            int gr = gidx >> 4, sl = gidx & 15;
            int lo = gr << 4, hi = lo + 16, fok = 0;
            for (int x = 0; x < 8; ++x)
                if (pre[x] <= lo && hi <= pre[x + 1]) fok = 1;
            sA[0] = gr; sA[1] = sl; sA[2] = fok;
        }
        __syncthreads();
        group = sA[0]; slot = sA[1]; fastm = (sA[2] != 0);
    } else {
        group = bid / WGSPC; slot = bid % WGSPC; fastm = false;
    }

    uint* abortp = abortf + group;
    const int wic     = slot * 4 + wave;       // wave-in-chain 0..63
    const int rowbase = slot * 64 + wave * 16; // this wave's 16 rows
    const int rowwg   = slot * 64;

    // ---- one-time: stage the WG's 64 W_hh rows into LDS as bf16 pairs ----
    for (int idx = tid; idx < 64 * 512; idx += BLOCK) {
        const int r = idx >> 9, p = idx & 511;
        const float2 w = *(const float2*)&W_hh[(size_t)(rowwg + r) * H + 2 * p];
        sW[r][p] = f2bf(w.x) | (f2bf(w.y) << 16);
    }
    __syncthreads();

    const int myrow = rowbase + (lane & 15);
    const float wih_s = W_ih[myrow];
    const float cb_s  = b_ih[myrow] + b_hh[myrow];

    f32x4 wo4[4];
    #pragma unroll
    for (int q = 0; q < 4; ++q)
        wo4[q] = *(const f32x4*)&W_out[256 * q + 4 * lane];
    const float bo = b_out[0];

    float hr[16];
    float lv0[4] = {0,0,0,0}, lv1[4] = {0,0,0,0};
    uint  lastflag[4] = {0,0,0,0};
    float xcur[4];
    #pragma unroll
    for (int k = 0; k < 4; ++k) {
        if (k < ilv) {
            const int ck = group * ilv + k;
            xcur[k] = xs[ck * chunk - (ck ? WARM : 0)];
        } else xcur[k] = 0.0f;
    }

    // demote whole group to LLC protocol (values bitwise-identical)
    auto demote = [&]() {
        #pragma unroll
        for (int k = 0; k < 4; ++k) {
            if (k >= ilv) continue;
            const int ck = group * ilv + k;
            float* hbk = hdata + (size_t)ck * 2 * H;
            float* q0 = hbk + rowbase + (lane & 15);
            float* q1 = q0 + H;
            if (lane < 16) {
                asm volatile("global_store_dword %0, %1, off sc0 sc1"
                             :: "v"(q0), "v"(lv0[k]) : "memory");
                asm volatile("global_store_dword %0, %1, off sc0 sc1"
                             :: "v"(q1), "v"(lv1[k]) : "memory");
            }
            asm volatile("s_waitcnt vmcnt(0)" ::: "memory");
            if (lane == 0)
                asm volatile("global_store_dword %0, %1, off sc0 sc1"
                             :: "v"(flbase + ck * 64 + wic), "v"(lastflag[k]) : "memory");
        }
        asm volatile("s_waitcnt vmcnt(0)" ::: "memory");
        if (lane == 0)
            asm volatile("global_store_dword %0, %1, off sc0 sc1"
                         :: "v"(abortp), "v"(1u) : "memory");
        asm volatile("s_waitcnt vmcnt(0)" ::: "memory");
        fastm = false;
    };

    auto abort_set = [&]() -> bool {
        uint ab;
        asm volatile("global_load_dword %0, %1, off sc0 sc1\n\ts_waitcnt vmcnt(0)"
                     : "=v"(ab) : "v"(abortp) : "memory");
        return __any(ab != 0u);
    };

    // wait until all 64 wave-flags of chain ck >= lt, then load h (parity lt&1)
    auto poll_load = [&](int ck, int lt) {
        const uint* fa = flbase + ck * 64 + lane;
        const uint tt = (uint)lt;
        uint fails = 0;
        for (;;) {
            uint f;
            if (fastm)
                asm volatile("global_load_dword %0, %1, off sc0\n\ts_waitcnt vmcnt(0)"
                             : "=v"(f) : "v"(fa) : "memory");
            else
                asm volatile("global_load_dword %0, %1, off sc0 sc1\n\ts_waitcnt vmcnt(0)"
                             : "=v"(f) : "v"(fa) : "memory");
            if (__all(f >= tt)) break;
            ++fails;
            if (fastm) {
                if ((fails & 63u) == 0u) {
                    if (abort_set() || fails > 8192u) demote();
                }
                __builtin_amdgcn_s_sleep(1);
            } else {
                __builtin_amdgcn_s_sleep(8);
            }
        }
        const float* a = hdata + (size_t)ck * 2 * H + (size_t)(lt & 1) * H + 4 * lane;
        f32x4 A, B, C, D;
        if (fastm)
            asm volatile(
                "global_load_dwordx4 %0, %4, off sc0\n\t"
                "global_load_dwordx4 %1, %4, off offset:1024 sc0\n\t"
                "global_load_dwordx4 %2, %4, off offset:2048 sc0\n\t"
                "global_load_dwordx4 %3, %4, off offset:3072 sc0\n\t"
                "s_waitcnt vmcnt(0)"
                : "=&v"(A), "=&v"(B), "=&v"(C), "=&v"(D) : "v"(a) : "memory");
        else
            asm volatile(
                "global_load_dwordx4 %0, %4, off sc0 sc1\n\t"
                "global_load_dwordx4 %1, %4, off offset:1024 sc0 sc1\n\t"
                "global_load_dwordx4 %2, %4, off offset:2048 sc0 sc1\n\t"
                "global_load_dwordx4 %3, %4, off offset:3072 sc0 sc1\n\t"
                "s_waitcnt vmcnt(0)"
                : "=&v"(A), "=&v"(B), "=&v"(C), "=&v"(D) : "v"(a) : "memory");
        #pragma unroll
        for (int kk = 0; kk < 4; ++kk) {
            hr[kk] = A[kk]; hr[4 + kk] = B[kk]; hr[8 + kk] = C[kk]; hr[12 + kk] = D[kk];
        }
    };

    const int nstep_max = chunk + WARM;

    #pragma unroll 1
    for (int it = 0; it < nstep_max; ++it) {
        if (fastm && (it & 31) == 1) {          // producer-side liveness
            if (abort_set()) demote();
        }

        #pragma unroll
        for (int k = 0; k < 4; ++k) {
            if (k >= ilv) continue;
            const int ck = group * ilv + k;
            const int warm_k  = ck ? WARM : 0;
            const int nstep_k = chunk + warm_k;
            if (it >= nstep_k) continue;
            const int t0_k = ck * chunk - warm_k;

            poll_load(ck, it);                  // hr = h_it of chain ck

            // 16 row-dots from LDS bf16 pairs
            float z[RPW];
            #pragma unroll
            for (int r = 0; r < RPW; ++r) {
                const uint2* wrow = (const uint2*)&sW[wave * RPW + r][2 * lane];
                float acc = 0.0f;
                #pragma unroll
                for (int q = 0; q < 4; ++q) {
                    const uint2 u = wrow[q * 64];
                    acc = fmaf(__uint_as_float(u.x << 16),         hr[4 * q + 0], acc);
                    acc = fmaf(__uint_as_float(u.x & 0xffff0000u), hr[4 * q + 1], acc);
                    acc = fmaf(__uint_as_float(u.y << 16),         hr[4 * q + 2], acc);
                    acc = fmaf(__uint_as_float(u.y & 0xffff0000u), hr[4 * q + 3], acc);
                }
                z[r] = acc;
            }

            // tree transpose-reduce: lane l ends with z of row rowbase+(l&15)
            float s0,s1,s2,s3,s4,s5,s6,s7;
            {
                const bool b = (lane & 1) != 0;
                s0 = (b ? z[ 1] : z[ 0]) + __shfl_xor(b ? z[ 0] : z[ 1], 1);
                s1 = (b ? z[ 3] : z[ 2]) + __shfl_xor(b ? z[ 2] : z[ 3], 1);
                s2 = (b ? z[ 5] : z[ 4]) + __shfl_xor(b ? z[ 4] : z[ 5], 1);
                s3 = (b ? z[ 7] : z[ 6]) + __shfl_xor(b ? z[ 6] : z[ 7], 1);
                s4 = (b ? z[ 9] : z[ 8]) + __shfl_xor(b ? z[ 8] : z[ 9], 1);
                s5 = (b ? z[11] : z[10]) + __shfl_xor(b ? z[10] : z[11], 1);
                s6 = (b ? z[13] : z[12]) + __shfl_xor(b ? z[12] : z[13], 1);
                s7 = (b ? z[15] : z[14]) + __shfl_xor(b ? z[14] : z[15], 1);
            }
            float t0_,t1_,t2_,t3_;
            {
                const bool b = (lane & 2) != 0;
                t0_ = (b ? s1 : s0) + __shfl_xor(b ? s0 : s1, 2);
                t1_ = (b ? s3 : s2) + __shfl_xor(b ? s2 : s3, 2);
                t2_ = (b ? s5 : s4) + __shfl_xor(b ? s4 : s5, 2);
                t3_ = (b ? s7 : s6) + __shfl_xor(b ? s6 : s7, 2);
            }
            float u0_,u1_;
            {
                const bool b = (lane & 4) != 0;
                u0_ = (b ? t1_ : t0_) + __shfl_xor(b ? t0_ : t1_, 4);
                u1_ = (b ? t3_ : t2_) + __shfl_xor(b ? t2_ : t3_, 4);
            }
            float zr;
            {
                const bool b = (lane & 8) != 0;
                zr = (b ? u1_ : u0_) + __shfl_xor(b ? u0_ : u1_, 8);
            }
            zr += __shfl_xor(zr, 16);
            zr += __shfl_xor(zr, 32);

            const float hv = tanhf(fmaf(xcur[k], wih_s, cb_s + zr));

            // publish: h store -> vmcnt(0) -> per-wave flag
            {
                float* hbk = hdata + (size_t)ck * 2 * H;
                float* dst = hbk + (size_t)((it + 1) & 1) * H + rowbase + (lane & 15);
                if (lane < 16) {
                    if (fastm)
                        asm volatile("global_store_dword %0, %1, off"
                                     :: "v"(dst), "v"(hv) : "memory");
                    else
                        asm volatile("global_store_dword %0, %1, off sc0 sc1"
                                     :: "v"(dst), "v"(hv) : "memory");
                }
                asm volatile("s_waitcnt vmcnt(0)" ::: "memory");
                const uint nf = (uint)(it + 1);
                if (lane == 0) {
                    if (fastm)
                        asm volatile("global_store_dword %0, %1, off"
                                     :: "v"(flbase + ck * 64 + wic), "v"(nf) : "memory");
                    else
                        asm volatile("global_store_dword %0, %1, off sc0 sc1"
                                     :: "v"(flbase + ck * 64 + wic), "v"(nf) : "memory");
                }
                if (((it + 1) & 1) == 0) lv0[k] = hv; else lv1[k] = hv;
                lastflag[k] = nf;
            }

            // y[t0+it-1]: duty wave (it mod 64)
            if (wic == (it & 63) && it >= warm_k + 1) {
                float acc = 0.0f;
                #pragma unroll
                for (int q = 0; q < 4; ++q) {
                    acc = fmaf(wo4[q][0], hr[4 * q + 0], acc);
                    acc = fmaf(wo4[q][1], hr[4 * q + 1], acc);
                    acc = fmaf(wo4[q][2], hr[4 * q + 2], acc);
                    acc = fmaf(wo4[q][3], hr[4 * q + 3], acc);
                }
                #pragma unroll
                for (int off = 32; off > 0; off >>= 1)
                    acc += __shfl_xor(acc, off);
                if (lane == 0) {
                    if (coop) sY[wave][k][it >> 6] = acc + bo;   // park in LDS
                    else      y[t0_k + it - 1] = acc + bo;       // fallback
                }
            }

            if (it + 1 < nstep_k) xcur[k] = xs[t0_k + it + 1];
        }
    }

    // ---- flush parked y (coop): it = 64*kk + wic -> y[t0+it-1] ----
    if (coop) {
        #pragma unroll
        for (int k = 0; k < 4; ++k) {
            if (k >= ilv) continue;
            const int ck = group * ilv + k;
            const int warm_k  = ck ? WARM : 0;
            const int nstep_k = chunk + warm_k;
            const int t0_k = ck * chunk - warm_k;
            #pragma unroll 1
            for (int kk = 0; kk < 8; ++kk) {
                const int it = (kk << 6) + wic;
                if (it >= warm_k + 1 && it < nstep_k && lane == 0)
                    ;   // value sits in sY[wave][k][kk] for lane 0's wave only
                if (it >= warm_k + 1 && it < nstep_k)
                    if (lane == 0) y[t0_k + it - 1] = sY[wave][k][kk];
            }
        }
    }

    // tail: y[t0+nstep-1] from h_nstep (one WG/wave per chain)
    if (slot == 0 && wave == 0) {
        #pragma unroll
        for (int k = 0; k < 4; ++k) {
            if (k >= ilv) continue;
            const int ck = group * ilv + k;
            const int warm_k  = ck ? WARM : 0;
            const int nstep_k = chunk + warm_k;
            const int t0_k = ck * chunk - warm_k;
            poll_load(ck, nstep_k);
            float acc = 0.0f;
            #pragma unroll
            for (int q = 0; q < 4; ++q) {
                acc = fmaf(wo4[q][0], hr[4 * q + 0], acc);
                acc = fmaf(wo4[q][1], hr[4 * q + 1], acc);
                acc = fmaf(wo4[q][2], hr[4 * q + 2], acc);
                acc = fmaf(wo4[q][3], hr[4 * q + 3], acc);
            }
            #pragma unroll
            for (int off = 32; off > 0; off >>= 1)
                acc += __shfl_xor(acc, off);
            if (lane == 0) y[t0_k + nstep_k - 1] = acc + bo;
        }
    }
}

extern "C" void kernel_launch(void* const* d_in, const int* in_sizes, int n_in,
                              void* d_out, int out_size, void* d_ws, size_t ws_size,
                              hipStream_t stream) {
    const float* xs    = (const float*)d_in[0];
    const float* W_ih  = (const float*)d_in[1];
    const float* b_ih  = (const float*)d_in[2];
    const float* W_hh  = (const float*)d_in[3];
    const float* b_hh  = (const float*)d_in[4];
    const float* W_out = (const float*)d_in[5];
    const float* b_out = (const float*)d_in[6];
    float* y = (float*)d_out;

    const size_t ctrl_bytes = 24576;
    const size_t need = HDATA_BYTES + ctrl_bytes;            // ~536 KB
    int use_coop = (ws_size >= need) ? 1 : 0;

    float* hdata = (float*)d_ws;
    uint*  ctrl  = (uint*)((char*)d_ws +
                           (use_coop ? HDATA_BYTES
                                     : (size_t)4 * 2 * H * sizeof(float)));

    (void)hipMemsetAsync(d_ws, 0,
                         use_coop ? need
                                  : (size_t)4 * 2 * H * sizeof(float) + ctrl_bytes,
                         stream);

    if (use_coop) {
        int coop = 1, ilv = 4, chunk = TSTEPS / 64;          // 64 chains x 320
        void* args[] = { (void*)&xs, (void*)&W_ih, (void*)&b_ih, (void*)&W_hh,
                         (void*)&b_hh, (void*)&W_out, (void*)&b_out, (void*)&y,
                         (void*)&hdata, (void*)&ctrl,
                         (void*)&coop, (void*)&ilv, (void*)&chunk };
        hipError_t e = hipLaunchCooperativeKernel((const void*)rnn_r18,
                                                  dim3(256), dim3(BLOCK),
                                                  args, 0, stream);
        if (e != hipSuccess) use_coop = 0;
    }
    if (!use_coop) {
        rnn_r18<<<4 * WGSPC, BLOCK, 0, stream>>>(
            xs, W_ih, b_ih, W_hh, b_hh, W_out, b_out, y,
            hdata, ctrl, 0, 1, TSTEPS / 4);
    }
}